// Round 3
// baseline (53.133 us; speedup 1.0000x reference)
//
#include <hip/hip_runtime.h>

// BeliefModuleOld: B=1e6, T=5, NTYPES=2, D=6
// in[0]: visible_treats [B,5,2,6] f32  (60 floats / batch = 15 float4)
// in[1]: vision         [B,5]     i32
// out:   [B,2,6] f32               (12 floats / batch = 3 float4)
//
// Fully-coalesced: treats AND vision staged to LDS via global_load_lds;
// compute from LDS; output staged in a separate LDS buffer (no aliasing
// barrier) and stored coalesced.

#define WPB 256

__device__ __forceinline__ void gload_lds16(const void* g, void* l) {
    __builtin_amdgcn_global_load_lds(
        (const __attribute__((address_space(1))) void*)g,
        (__attribute__((address_space(3))) void*)l, 16, 0, 0);
}
__device__ __forceinline__ void gload_lds4(const void* g, void* l) {
    __builtin_amdgcn_global_load_lds(
        (const __attribute__((address_space(1))) void*)g,
        (__attribute__((address_space(3))) void*)l, 4, 0, 0);
}

__global__ __launch_bounds__(256) void belief_kernel(
    const float4* __restrict__ vt4,
    const int*    __restrict__ vision,
    float4*       __restrict__ out4,
    int B)
{
    __shared__ float4 s_vt[WPB * 15];    // 61440 B treats tile
    __shared__ float4 s_out[WPB * 3];    // 12288 B output stage
    __shared__ int    s_vis[WPB * 5];    //  5120 B vision tile

    const int tid  = threadIdx.x;
    const int lane = tid & 63;
    const int wave = tid >> 6;

    const int blockBase = blockIdx.x * WPB;
    const int f4Total   = B * 15;
    const int f4Base    = blockBase * 15;

    // ---- stage treats: 3840 float4, direct-to-LDS, coalesced ----
#pragma unroll
    for (int i = 0; i < 15; ++i) {
        const int l = i * 256 + wave * 64;          // wave-uniform LDS f4 idx
        int g = f4Base + l + lane;
        if (g >= f4Total) g = f4Total - 1;          // tail clamp
        gload_lds16(vt4 + g, &s_vt[l]);
    }

    // ---- stage vision: 1280 ints, direct-to-LDS, coalesced ----
    const int vTotal = B * 5;
    const int vBase  = blockBase * 5;
#pragma unroll
    for (int i = 0; i < 5; ++i) {
        const int l = i * 256 + wave * 64;
        int g = vBase + l + lane;
        if (g >= vTotal) g = vTotal - 1;
        gload_lds4(vision + g, &s_vis[l]);
    }

    __syncthreads();   // drains vmcnt for all global_load_lds

    // ---- compute ----
    float o[12];
#pragma unroll
    for (int tt = 0; tt < 2; ++tt) {
        o[tt*6+0]=0.f; o[tt*6+1]=0.f; o[tt*6+2]=0.f;
        o[tt*6+3]=0.f; o[tt*6+4]=0.f; o[tt*6+5]=1.f;
    }

    const int fbase = tid * 15;
    const int vbase = tid * 5;
#pragma unroll
    for (int t = 0; t < 5; ++t) {
        float4 r0 = s_vt[fbase + t*3 + 0];   // tt0 d0..3
        float4 r1 = s_vt[fbase + t*3 + 1];   // tt0 d4,5 | tt1 d0,1
        float4 r2 = s_vt[fbase + t*3 + 2];   // tt1 d2..5
        const int vt_ = s_vis[vbase + t];

        // tt = 0
        {
            float m = fmaxf(fmaxf(fmaxf(r0.x, r0.y), fmaxf(r0.z, r0.w)), r1.x);
            if ((vt_ != 0) && (m > 0.5f)) {
                o[0]=r0.x; o[1]=r0.y; o[2]=r0.z; o[3]=r0.w; o[4]=r1.x; o[5]=r1.y;
            }
        }
        // tt = 1
        {
            float m = fmaxf(fmaxf(fmaxf(r1.z, r1.w), fmaxf(r2.x, r2.y)), r2.z);
            if ((vt_ != 0) && (m > 0.5f)) {
                o[6]=r1.z; o[7]=r1.w; o[8]=r2.x; o[9]=r2.y; o[10]=r2.z; o[11]=r2.w;
            }
        }
    }

    // s_out is a separate buffer — no barrier needed before writing it
    s_out[tid*3 + 0] = make_float4(o[0], o[1], o[2],  o[3]);
    s_out[tid*3 + 1] = make_float4(o[4], o[5], o[6],  o[7]);
    s_out[tid*3 + 2] = make_float4(o[8], o[9], o[10], o[11]);

    __syncthreads();

    const int oTotal = B * 3;
    const int oBase  = blockBase * 3;
#pragma unroll
    for (int i = 0; i < 3; ++i) {
        const int l = i * 256 + tid;
        const int g = oBase + l;
        if (g < oTotal) out4[g] = s_out[l];
    }
}

extern "C" void kernel_launch(void* const* d_in, const int* in_sizes, int n_in,
                              void* d_out, int out_size, void* d_ws, size_t ws_size,
                              hipStream_t stream) {
    const float4* vt4    = (const float4*)d_in[0];
    const int*    vision = (const int*)d_in[1];
    float4*       out4   = (float4*)d_out;
    int B = in_sizes[1] / 5;

    int grid = (B + WPB - 1) / WPB;
    belief_kernel<<<grid, WPB, 0, stream>>>(vt4, vision, out4, B);
}

// Round 4
// 52.833 us; speedup vs baseline: 1.0057x; 1.0057x over previous
//
#include <hip/hip_runtime.h>

// BeliefModuleOld: B=1e6, T=5, NTYPES=2, D=6
// in[0]: visible_treats [B,5,2,6] f32  (60 floats / batch = 15 float4)
// in[1]: vision         [B,5]     i32
// out:   [B,2,6] f32               (12 floats / batch = 3 float4)
//
// R2 configuration (proven 51.2 us = 6.02 TB/s effective, 96% of the
// measured float4-copy ceiling). R3's vision-LDS staging + separate out
// buffer regressed (LDS 77.8KB/block left no occupancy headroom; width-4
// global_load_lds is 4x less efficient per instruction) — reverted.

#define WPB 256

__device__ __forceinline__ void gload_lds16(const void* g, void* l) {
    __builtin_amdgcn_global_load_lds(
        (const __attribute__((address_space(1))) void*)g,
        (__attribute__((address_space(3))) void*)l, 16, 0, 0);
}

__global__ __launch_bounds__(256) void belief_kernel(
    const float4* __restrict__ vt4,
    const int*    __restrict__ vision,
    float4*       __restrict__ out4,
    int B)
{
    __shared__ float4 s_vt[WPB * 15];   // 61440 B; reused as output stage

    const int tid  = threadIdx.x;
    const int lane = tid & 63;
    const int wave = tid >> 6;

    const int blockBase = blockIdx.x * WPB;          // first batch of block
    const int f4Total   = B * 15;
    const int f4Base    = blockBase * 15;

    // ---- stage treats: 3840 float4 per block, direct-to-LDS, coalesced ----
#pragma unroll
    for (int i = 0; i < 15; ++i) {
        const int l = i * 256 + wave * 64;           // wave-uniform LDS f4 idx
        int g = f4Base + l + lane;                   // per-lane global f4 idx
        if (g >= f4Total) g = f4Total - 1;           // clamp (tail block)
        gload_lds16(vt4 + g, &s_vt[l]);
    }

    // ---- vision: direct strided (only 20B/thread; L1 absorbs) ----
    const int b = blockBase + tid;
    int v[5] = {0, 0, 0, 0, 0};
    if (b < B) {
        const int* vp = vision + b * 5;
#pragma unroll
        for (int t = 0; t < 5; ++t) v[t] = vp[t];
    }

    __syncthreads();   // drains global_load_lds (vmcnt) + barrier

    // ---- compute: scan over t, 3 ds_read_b128 per t ----
    float o[12];
#pragma unroll
    for (int tt = 0; tt < 2; ++tt) {
        o[tt*6+0]=0.f; o[tt*6+1]=0.f; o[tt*6+2]=0.f;
        o[tt*6+3]=0.f; o[tt*6+4]=0.f; o[tt*6+5]=1.f;
    }

    const int fbase = tid * 15;     // this thread's batch: float4 base in LDS
#pragma unroll
    for (int t = 0; t < 5; ++t) {
        float4 r0 = s_vt[fbase + t*3 + 0];   // tt0 d0..3
        float4 r1 = s_vt[fbase + t*3 + 1];   // tt0 d4,5 | tt1 d0,1
        float4 r2 = s_vt[fbase + t*3 + 2];   // tt1 d2..5

        // tt = 0
        {
            float m = fmaxf(fmaxf(fmaxf(r0.x, r0.y), fmaxf(r0.z, r0.w)), r1.x);
            if ((v[t] != 0) && (m > 0.5f)) {
                o[0]=r0.x; o[1]=r0.y; o[2]=r0.z; o[3]=r0.w; o[4]=r1.x; o[5]=r1.y;
            }
        }
        // tt = 1
        {
            float m = fmaxf(fmaxf(fmaxf(r1.z, r1.w), fmaxf(r2.x, r2.y)), r2.z);
            if ((v[t] != 0) && (m > 0.5f)) {
                o[6]=r1.z; o[7]=r1.w; o[8]=r2.x; o[9]=r2.y; o[10]=r2.z; o[11]=r2.w;
            }
        }
    }

    __syncthreads();   // all treats reads done before aliasing as out stage

    // ---- stage output tile (alias s_vt), then coalesced store ----
    float4* s_out = s_vt;                      // 768 float4 used
    s_out[tid*3 + 0] = make_float4(o[0], o[1], o[2],  o[3]);
    s_out[tid*3 + 1] = make_float4(o[4], o[5], o[6],  o[7]);
    s_out[tid*3 + 2] = make_float4(o[8], o[9], o[10], o[11]);

    __syncthreads();

    const int oTotal = B * 3;
    const int oBase  = blockBase * 3;
#pragma unroll
    for (int i = 0; i < 3; ++i) {
        const int l = i * 256 + tid;
        const int g = oBase + l;
        if (g < oTotal) out4[g] = s_out[l];
    }
}

extern "C" void kernel_launch(void* const* d_in, const int* in_sizes, int n_in,
                              void* d_out, int out_size, void* d_ws, size_t ws_size,
                              hipStream_t stream) {
    const float4* vt4    = (const float4*)d_in[0];
    const int*    vision = (const int*)d_in[1];
    float4*       out4   = (float4*)d_out;
    int B = in_sizes[1] / 5;   // vision is [B,5]

    int grid = (B + WPB - 1) / WPB;
    belief_kernel<<<grid, WPB, 0, stream>>>(vt4, vision, out4, B);
}